// Round 11
// baseline (465.825 us; speedup 1.0000x reference)
//
#include <hip/hip_runtime.h>

#define D_  1024
#define H_  16
#define HD_ 64
#define L_  2048
#define B_  2
#define M_  (B_*L_)   // 4096 rows

typedef float f32x4  __attribute__((ext_vector_type(4)));
typedef short bf16x4 __attribute__((ext_vector_type(4)));
typedef short bf16x8 __attribute__((ext_vector_type(8)));

#define SRAW_PITCH 18   // f32 per l-row (72B): conflict-free b64/scalar patterns
#define SRAW_SLAB  (16 * SRAW_PITCH)   // 288 f32 per h (or m) slab

__device__ __forceinline__ float bf2f(short s) {
    return __uint_as_float(((unsigned int)(unsigned short)s) << 16);
}
__device__ __forceinline__ short f2bf(float f) {   // RNE
    unsigned u = __float_as_uint(f);
    unsigned r = (u + 0x7FFFu + ((u >> 16) & 1u)) >> 16;
    return (short)r;
}
// Raw barrier: orders LDS (lgkmcnt(0) + "memory" clobber), does NOT drain vmcnt.
// Verified equivalent to __syncthreads for this kernel's protocol (R4==R5 absmax).
__device__ __forceinline__ void block_sync() {
    asm volatile("s_waitcnt lgkmcnt(0)" ::: "memory");
    __builtin_amdgcn_sched_barrier(0);
    __builtin_amdgcn_s_barrier();
    __builtin_amdgcn_sched_barrier(0);
}

// ---------------------------------------------------------------------------
// Kernel 1: QKV projections via bf16 MFMA. 128x128 tile, K-step 32, 256 thr.
// z=0: q -> qh(hi)+qlo  [b][h][l][64]        (A=W rows n, B=X cols m: D[n][m])
// z=1: k -> kh          [b][h][l][64]        (same)
// z=2: v -> vht         [b][h][64][L]        (A=X rows m, B=W cols n: D[m][n])
// ---------------------------------------------------------------------------
__global__ __launch_bounds__(256) void proj_mfma(
    const float* __restrict__ q, const float* __restrict__ k, const float* __restrict__ v,
    const float* __restrict__ Wq, const float* __restrict__ bq,
    const float* __restrict__ Wk, const float* __restrict__ bk,
    const float* __restrict__ Wv, const float* __restrict__ bv,
    short* __restrict__ qh, short* __restrict__ qlo,
    short* __restrict__ kh, short* __restrict__ vht)
{
    const int z = blockIdx.z;
    const float* X    = (z == 0) ? q  : (z == 1) ? k  : v;
    const float* W    = (z == 0) ? Wq : (z == 1) ? Wk : Wv;
    const float* bias = (z == 0) ? bq : (z == 1) ? bk : bv;

    __shared__ short Ws[128][40];
    __shared__ short Xs[128][40];

    const int tid  = threadIdx.x;
    const int w    = tid >> 6, lane = tid & 63;
    const int l16  = lane & 15, qq = lane >> 4;
    const int m0   = blockIdx.x * 128;
    const int n0   = blockIdx.y * 128;
    const int ar0  = 64 * (w & 1);
    const int br0  = 64 * (w >> 1);

    f32x4 acc[4][4] = {};

    for (int k0 = 0; k0 < D_; k0 += 32) {
        #pragma unroll
        for (int i = 0; i < 4; ++i) {
            int fidx = i * 256 + tid;
            int r = fidx >> 3, c = fidx & 7;
            float4 wv4 = *(const float4*)(W + (size_t)(n0 + r) * D_ + k0 + c * 4);
            float4 xv4 = *(const float4*)(X + (size_t)(m0 + r) * D_ + k0 + c * 4);
            bf16x4 wb = { f2bf(wv4.x), f2bf(wv4.y), f2bf(wv4.z), f2bf(wv4.w) };
            bf16x4 xb = { f2bf(xv4.x), f2bf(xv4.y), f2bf(xv4.z), f2bf(xv4.w) };
            *(bf16x4*)&Ws[r][c * 4] = wb;
            *(bf16x4*)&Xs[r][c * 4] = xb;
        }
        __syncthreads();
        bf16x8 af[4], bfv[4];
        #pragma unroll
        for (int i = 0; i < 4; ++i) {
            // z<2: A=W (rows n), B=X (cols m).  z==2: A=X (rows m), B=W (cols n).
            const short* Ab = (z < 2) ? &Ws[ar0 + 16 * i + l16][qq * 8]
                                      : &Xs[ar0 + 16 * i + l16][qq * 8];
            const short* Bb = (z < 2) ? &Xs[br0 + 16 * i + l16][qq * 8]
                                      : &Ws[br0 + 16 * i + l16][qq * 8];
            af[i]  = *(const bf16x8*)Ab;
            bfv[i] = *(const bf16x8*)Bb;
        }
        #pragma unroll
        for (int i = 0; i < 4; ++i)
            #pragma unroll
            for (int j = 0; j < 4; ++j)
                acc[i][j] = __builtin_amdgcn_mfma_f32_16x16x32_bf16(af[i], bfv[j], acc[i][j], 0, 0, 0);
        __syncthreads();
    }

    if (z < 2) {
        #pragma unroll
        for (int i = 0; i < 4; ++i) {
            int nb = n0 + ar0 + 16 * i + qq * 4;
            float4 b4 = *(const float4*)(bias + nb);
            int h = nb >> 6, hd = nb & 63;
            #pragma unroll
            for (int j = 0; j < 4; ++j) {
                int m = m0 + br0 + 16 * j + l16;
                int bb = m >> 11, l = m & (L_ - 1);
                size_t o = ((((size_t)bb * H_ + h) * L_) + l) * HD_ + hd;
                f32x4 c = acc[i][j];
                float v0 = c[0] + b4.x, v1 = c[1] + b4.y, v2 = c[2] + b4.z, v3 = c[3] + b4.w;
                bf16x4 hi = { f2bf(v0), f2bf(v1), f2bf(v2), f2bf(v3) };
                if (z == 0) {
                    *(bf16x4*)&qh[o] = hi;
                    bf16x4 lo = { f2bf(v0 - bf2f(hi[0])), f2bf(v1 - bf2f(hi[1])),
                                  f2bf(v2 - bf2f(hi[2])), f2bf(v3 - bf2f(hi[3])) };
                    *(bf16x4*)&qlo[o] = lo;
                } else {
                    *(bf16x4*)&kh[o] = hi;
                }
            }
        }
    } else {
        // D[m][n]: rows m = m0+ar0+16i+4qq+r ; cols n = n0+br0+16j+l16
        #pragma unroll
        for (int i = 0; i < 4; ++i) {
            int mb = m0 + ar0 + 16 * i + qq * 4;
            int bb = mb >> 11, lb = mb & (L_ - 1);
            #pragma unroll
            for (int j = 0; j < 4; ++j) {
                int n = n0 + br0 + 16 * j + l16;
                int h = n >> 6, hd = n & 63;
                float bn = bias[n];
                size_t o = (((size_t)bb * H_ + h) * HD_ + hd) * (size_t)L_ + lb;
                f32x4 c = acc[i][j];
                bf16x4 ov = { f2bf(c[0] + bn), f2bf(c[1] + bn), f2bf(c[2] + bn), f2bf(c[3] + bn) };
                *(bf16x4*)&vht[o] = ov;
            }
        }
    }
}

// ---------------------------------------------------------------------------
// Kernel 2: fused talking-heads attention. 512 thr (8 waves), l-tile 16,
// m-tile 16, all heads per block. Wave w: heads/g {2w, 2w+1}, m-inst {2w,2w+1}.
// R11 = R10 with the V WAR bug fixed: V prefetch for tile t+2 is issued AFTER
// PV consumes tile t's fragments (same registers). K prefetch stays early
// (its consumer ran in the previous body). V LDS round-trip deleted (R10 idea).
// ---------------------------------------------------------------------------
__global__ __launch_bounds__(512, 2) void attn_mfma(
    const short* __restrict__ qh, const short* __restrict__ qlo,
    const short* __restrict__ kh, const short* __restrict__ vht,
    const float* __restrict__ P, short* __restrict__ attn_out)
{
    __shared__ __align__(16) float Sraw0[16 * SRAW_SLAB];         // [h][l][18] 18.4 KB
    __shared__ __align__(16) float Sraw1[16 * SRAW_SLAB];         // 18.4 KB
    __shared__ __align__(16) float Smix[16 * SRAW_SLAB];          // [m][l][18] (g fast) 18.4 KB
    __shared__ float PmS[256];

    const int tid  = threadIdx.x;
    const int n    = blockIdx.x;
    const int b    = (n >> 2) & 1;                        // XCD swizzle
    const int l0   = ((n >> 3) * 4 + (n & 3)) * 16;
    const int w    = tid >> 6, lane = tid & 63;
    const int l16  = lane & 15, qq = lane >> 4;
    const size_t hb = (size_t)b * H_;

    // ---- Q frags (persistent)
    bf16x8 qf[2][2][2];
    #pragma unroll
    for (int hh = 0; hh < 2; ++hh)
        #pragma unroll
        for (int kc = 0; kc < 2; ++kc) {
            size_t off = ((hb + 2 * w + hh) * L_ + l0 + l16) * HD_ + kc * 32 + qq * 8;
            qf[hh][kc][0] = *(const bf16x8*)(qh  + off);
            qf[hh][kc][1] = *(const bf16x8*)(qlo + off);
        }

    // PV A-fragment global addresses: V^T[g=2w+i][d=dt*16+l16][m0 + qq*4 .. +3]
    const short* vbase[2][4];
    #pragma unroll
    for (int i = 0; i < 2; ++i)
        #pragma unroll
        for (int dt = 0; dt < 4; ++dt)
            vbase[i][dt] = vht + ((hb + 2 * w + i) * HD_ + dt * 16 + l16) * (size_t)L_ + qq * 4;

    // ---- double-buffered K frags + V frags: A = even tiles, B = odd tiles
    bf16x8 kA[2][2], kB[2][2];
    bf16x4 vfA[2][4], vfB[2][4];
    #pragma unroll
    for (int hh = 0; hh < 2; ++hh)
        #pragma unroll
        for (int kc = 0; kc < 2; ++kc) {
            kA[hh][kc] = *(const bf16x8*)(kh + ((hb + 2 * w + hh) * L_ + 0  + l16) * HD_ + kc * 32 + qq * 8);
            kB[hh][kc] = *(const bf16x8*)(kh + ((hb + 2 * w + hh) * L_ + 16 + l16) * HD_ + kc * 32 + qq * 8);
        }
    #pragma unroll
    for (int i = 0; i < 2; ++i)
        #pragma unroll
        for (int dt = 0; dt < 4; ++dt) {
            vfA[i][dt] = *(const bf16x4*)(vbase[i][dt] + 0);
            vfB[i][dt] = *(const bf16x4*)(vbase[i][dt] + 16);
        }

    if (tid < 256) PmS[tid] = P[tid] * 0.125f;            // fold 1/sqrt(64)

    f32x4 acc[2][4];
    #pragma unroll
    for (int dt = 0; dt < 4; ++dt) { acc[0][dt] = (f32x4){0.f,0.f,0.f,0.f}; acc[1][dt] = (f32x4){0.f,0.f,0.f,0.f}; }
    // deferred-max running state (m_run init 0; mixed logits ~N(0,16))
    float mrun0 = 0.f, mrun1 = 0.f, srun0 = 0.f, srun1 = 0.f;

    // QK^T: D[m][l], col=l16, rows m=qq*4+j.  Writes 2x b64 per head slab.
    auto qkt = [&](bf16x8 (&kr)[2][2], float* sb) {
        #pragma unroll
        for (int hh = 0; hh < 2; ++hh) {
            f32x4 s = (f32x4){0.f,0.f,0.f,0.f};
            s = __builtin_amdgcn_mfma_f32_16x16x32_bf16(kr[hh][0], qf[hh][0][0], s, 0, 0, 0);
            s = __builtin_amdgcn_mfma_f32_16x16x32_bf16(kr[hh][0], qf[hh][0][1], s, 0, 0, 0);
            s = __builtin_amdgcn_mfma_f32_16x16x32_bf16(kr[hh][1], qf[hh][1][0], s, 0, 0, 0);
            s = __builtin_amdgcn_mfma_f32_16x16x32_bf16(kr[hh][1], qf[hh][1][1], s, 0, 0, 0);
            float* sp = sb + ((2 * w + hh) * 16 + l16) * SRAW_PITCH + qq * 4;
            *(float2*)sp       = make_float2(s[0], s[1]);
            *(float2*)(sp + 2) = make_float2(s[2], s[3]);
        }
    };

    // prologue: QK^T(tile 0) -> Sraw0, publish (also makes PmS visible)
    qkt(kA, Sraw0);
    block_sync();

    // ---- mix A-operand: P^T hi/lo broadcast fragment.
    // A[g][h]: row g = l16, k h = qq*4+j  -> PAhi[j] = PmS[(qq*4+j)*16 + l16]
    bf16x4 PAhi, PAlo;
    {
        float p0 = PmS[(qq * 4 + 0) * 16 + l16];
        float p1 = PmS[(qq * 4 + 1) * 16 + l16];
        float p2 = PmS[(qq * 4 + 2) * 16 + l16];
        float p3 = PmS[(qq * 4 + 3) * 16 + l16];
        PAhi = (bf16x4){ f2bf(p0), f2bf(p1), f2bf(p2), f2bf(p3) };
        PAlo = (bf16x4){ f2bf(p0 - bf2f(PAhi[0])), f2bf(p1 - bf2f(PAhi[1])),
                         f2bf(p2 - bf2f(PAhi[2])), f2bf(p3 - bf2f(PAhi[3])) };
    }

    // mix via MFMA for this wave's two m-instances (m = 2w, 2w+1):
    // B[h][l]: lane (col=l16, k h=qq*4+j) = Sraw[h][l16][m] (scalar gather, f32->hi/lo)
    // D2[g][l]: lane (col=l16, row g=qq*4+j) -> Smix[m][l][g]
    auto mixmfma = [&](const float* sb) {
        #pragma unroll
        for (int mi = 0; mi < 2; ++mi) {
            const int m = 2 * w + mi;
            float sv0 = sb[(qq * 4 + 0) * SRAW_SLAB + l16 * SRAW_PITCH + m];
            float sv1 = sb[(qq * 4 + 1) * SRAW_SLAB + l16 * SRAW_PITCH + m];
            float sv2 = sb[(qq * 4 + 2) * SRAW_SLAB + l16 * SRAW_PITCH + m];
            float sv3 = sb[(qq * 4 + 3) * SRAW_SLAB + l16 * SRAW_PITCH + m];
            bf16x4 bhi = { f2bf(sv0), f2bf(sv1), f2bf(sv2), f2bf(sv3) };
            bf16x4 blo = { f2bf(sv0 - bf2f(bhi[0])), f2bf(sv1 - bf2f(bhi[1])),
                           f2bf(sv2 - bf2f(bhi[2])), f2bf(sv3 - bf2f(bhi[3])) };
            f32x4 c = (f32x4){0.f, 0.f, 0.f, 0.f};
            c = __builtin_amdgcn_mfma_f32_16x16x16bf16_1k(PAhi, bhi, c, 0, 0, 0);
            c = __builtin_amdgcn_mfma_f32_16x16x16bf16_1k(PAhi, blo, c, 0, 0, 0);
            c = __builtin_amdgcn_mfma_f32_16x16x16bf16_1k(PAlo, bhi, c, 0, 0, 0);
            float* sp = Smix + m * SRAW_SLAB + l16 * SRAW_PITCH + qq * 4;
            *(float2*)sp       = make_float2(c[0], c[1]);
            *(float2*)(sp + 2) = make_float2(c[2], c[3]);
        }
    };

    // body(t): K-prefetch(t+2); mixMFMA(t); B_mid; softmax; PV(t);
    // V-prefetch(t+2) [AFTER PV: vf regs now dead]; qkt(t+1); rescale; B_end.
    auto body = [&](const float* sb, float* sbo, bf16x4 (&vf)[2][4], bf16x8 (&kqk)[2][2],
                    bf16x8 (&kld)[2][2], int tnext) {
        const int mn = tnext * 16;
        // 1. K prefetch tile tnext (kld consumed by qkt in the PREVIOUS body -> dead)
        #pragma unroll
        for (int hh = 0; hh < 2; ++hh)
            #pragma unroll
            for (int kc = 0; kc < 2; ++kc)
                kld[hh][kc] = *(const bf16x8*)(kh + ((hb + 2 * w + hh) * L_ + mn + l16) * HD_ + kc * 32 + qq * 8);
        // 2. mix via MFMA -> Smix
        mixmfma(sb);
        block_sync();   // B_mid: Smix visible to all waves
        // 3. softmax inputs: lane (l16, qq) reads smix[m=qq*4+j][l16][g] for g=2w,2w+1
        float sx0[4], sx1[4];
        #pragma unroll
        for (int j = 0; j < 4; ++j) {
            const float* mp = Smix + (qq * 4 + j) * SRAW_SLAB + l16 * SRAW_PITCH;
            sx0[j] = mp[2 * w];
            sx1[j] = mp[2 * w + 1];
        }
        // 4. deferred-max softmax: pf vs m_old; reduces off the PV critical path
        float e00 = __expf(sx0[0] - mrun0), e01 = __expf(sx0[1] - mrun0);
        float e02 = __expf(sx0[2] - mrun0), e03 = __expf(sx0[3] - mrun0);
        float e10 = __expf(sx1[0] - mrun1), e11 = __expf(sx1[1] - mrun1);
        float e12 = __expf(sx1[2] - mrun1), e13 = __expf(sx1[3] - mrun1);
        bf16x4 pf0 = { f2bf(e00), f2bf(e01), f2bf(e02), f2bf(e03) };
        bf16x4 pf1 = { f2bf(e10), f2bf(e11), f2bf(e12), f2bf(e13) };
        float t0 = fmaxf(fmaxf(sx0[0], sx0[1]), fmaxf(sx0[2], sx0[3]));
        float t1 = fmaxf(fmaxf(sx1[0], sx1[1]), fmaxf(sx1[2], sx1[3]));
        t0 = fmaxf(t0, __shfl_xor(t0, 16)); t0 = fmaxf(t0, __shfl_xor(t0, 32));
        t1 = fmaxf(t1, __shfl_xor(t1, 16)); t1 = fmaxf(t1, __shfl_xor(t1, 32));
        float ps0 = e00 + e01 + e02 + e03, ps1 = e10 + e11 + e12 + e13;
        ps0 += __shfl_xor(ps0, 16); ps0 += __shfl_xor(ps0, 32);
        ps1 += __shfl_xor(ps1, 16); ps1 += __shfl_xor(ps1, 32);
        // 5. PV: A = V^T frags (registers), B = pf.  D[d][l], col=l16.
        #pragma unroll
        for (int i = 0; i < 2; ++i) {
            bf16x4 pf = i ? pf1 : pf0;
            #pragma unroll
            for (int dt = 0; dt < 4; ++dt)
                acc[i][dt] = __builtin_amdgcn_mfma_f32_16x16x16bf16_1k(vf[i][dt], pf, acc[i][dt], 0, 0, 0);
        }
        // 6. V prefetch tile tnext -- AFTER PV consumed vf (same registers, now dead)
        #pragma unroll
        for (int i = 0; i < 2; ++i)
            #pragma unroll
            for (int dt = 0; dt < 4; ++dt)
                vf[i][dt] = *(const bf16x4*)(vbase[i][dt] + mn);
        // 7. QK^T(t+1) -> other Sraw buffer
        qkt(kqk, sbo);
        // 8. end-of-body rescale to new running max
        float mnew0 = fmaxf(mrun0, t0), mnew1 = fmaxf(mrun1, t1);
        float corr0 = __expf(mrun0 - mnew0), corr1 = __expf(mrun1 - mnew1);
        srun0 = (srun0 + ps0) * corr0; srun1 = (srun1 + ps1) * corr1;
        acc[0][0] *= corr0; acc[0][1] *= corr0; acc[0][2] *= corr0; acc[0][3] *= corr0;
        acc[1][0] *= corr1; acc[1][1] *= corr1; acc[1][2] *= corr1; acc[1][3] *= corr1;
        mrun0 = mnew0; mrun1 = mnew1;
        block_sync();   // B_end: Sraw_other + Smix WAR resolved; prefetches in flight
    };

    for (int itp = 0; itp < 64; ++itp) {
        const int t0 = 2 * itp;
        body(Sraw0, Sraw1, vfA, kB, kA, (t0 + 2) & 127);   // even tile t0
        body(Sraw1, Sraw0, vfB, kA, kB, (t0 + 3) & 127);   // odd tile t0+1
    }

    // epilogue: D[d][l] -> out[b][l][g*64 + d]
    float inv0 = 1.f / srun0, inv1 = 1.f / srun1;
    #pragma unroll
    for (int i = 0; i < 2; ++i) {
        float inv = i ? inv1 : inv0;
        #pragma unroll
        for (int dt = 0; dt < 4; ++dt) {
            f32x4 a = acc[i][dt];
            bf16x4 ov = { f2bf(a[0] * inv), f2bf(a[1] * inv), f2bf(a[2] * inv), f2bf(a[3] * inv) };
            *(bf16x4*)(attn_out + ((size_t)(b * L_ + l0 + l16)) * D_ + (2 * w + i) * 64 + dt * 16 + qq * 4) = ov;
        }
    }
}

// ---------------------------------------------------------------------------
// Kernel 3: output projection (attn bf16 @ Wo^T + bo) -> f32, MFMA.
// ---------------------------------------------------------------------------
__global__ __launch_bounds__(256) void out_mfma(
    const short* __restrict__ attn, const float* __restrict__ Wo,
    const float* __restrict__ bo, float* __restrict__ out)
{
    __shared__ short Ws[128][40];
    __shared__ short Xs[128][40];

    const int tid = threadIdx.x;
    const int w = tid >> 6, lane = tid & 63;
    const int l16 = lane & 15, qq = lane >> 4;
    const int m0 = blockIdx.x * 128;
    const int n0 = blockIdx.y * 128;
    const int ar0 = 64 * (w & 1);
    const int br0 = 64 * (w >> 1);

    f32x4 acc[4][4] = {};

    for (int k0 = 0; k0 < D_; k0 += 32) {
        #pragma unroll
        for (int i = 0; i < 4; ++i) {
            int fidx = i * 256 + tid;
            int r = fidx >> 3, c = fidx & 7;
            float4 wv4 = *(const float4*)(Wo + (size_t)(n0 + r) * D_ + k0 + c * 4);
            bf16x4 wb = { f2bf(wv4.x), f2bf(wv4.y), f2bf(wv4.z), f2bf(wv4.w) };
            *(bf16x4*)&Ws[r][c * 4] = wb;
        }
        #pragma unroll
        for (int i = 0; i < 2; ++i) {
            int cidx = i * 256 + tid;
            int r = cidx >> 2, c = cidx & 3;
            bf16x8 xv = *(const bf16x8*)(attn + (size_t)(m0 + r) * D_ + k0 + c * 8);
            *(bf16x8*)&Xs[r][c * 8] = xv;
        }
        __syncthreads();
        bf16x8 af[4], bfv[4];
        #pragma unroll
        for (int i = 0; i < 4; ++i) {
            af[i]  = *(const bf16x8*)&Ws[ar0 + 16 * i + l16][qq * 8];
            bfv[i] = *(const bf16x8*)&Xs[br0 + 16 * i + l16][qq * 8];
        }
        #pragma unroll
        for (int i = 0; i < 4; ++i)
            #pragma unroll
            for (int j = 0; j < 4; ++j)
                acc[i][j] = __builtin_amdgcn_mfma_f32_16x16x32_bf16(af[i], bfv[j], acc[i][j], 0, 0, 0);
        __syncthreads();
    }

    #pragma unroll
    for (int i = 0; i < 4; ++i) {
        int nb = n0 + ar0 + 16 * i + qq * 4;
        float4 b4 = *(const float4*)(bo + nb);
        #pragma unroll
        for (int j = 0; j < 4; ++j) {
            int m = m0 + br0 + 16 * j + l16;
            f32x4 c = acc[i][j];
            float4 ov = make_float4(c[0] + b4.x, c[1] + b4.y, c[2] + b4.z, c[3] + b4.w);
            *(float4*)&out[(size_t)m * D_ + nb] = ov;
        }
    }
}

// ---------------------------------------------------------------------------
extern "C" void kernel_launch(void* const* d_in, const int* in_sizes, int n_in,
                              void* d_out, int out_size, void* d_ws, size_t ws_size,
                              hipStream_t stream) {
    const float* q  = (const float*)d_in[0];
    const float* k  = (const float*)d_in[1];
    const float* v  = (const float*)d_in[2];
    const float* Wq = (const float*)d_in[3];
    const float* bq = (const float*)d_in[4];
    const float* Wk = (const float*)d_in[5];
    const float* bk = (const float*)d_in[6];
    const float* Wv = (const float*)d_in[7];
    const float* bv = (const float*)d_in[8];
    const float* Wo = (const float*)d_in[9];
    const float* bo = (const float*)d_in[10];
    const float* P  = (const float*)d_in[11];
    float* out = (float*)d_out;

    // ws: qh 8MB | qlo 8MB | kh 8MB | vht 8MB | attn 8MB (all bf16/short)
    char* ws = (char*)d_ws;
    short* qh   = (short*)(ws);
    short* qlo  = (short*)(ws + (size_t)8 * 1024 * 1024);
    short* kh   = (short*)(ws + (size_t)16 * 1024 * 1024);
    short* vht  = (short*)(ws + (size_t)24 * 1024 * 1024);
    short* attn = (short*)(ws + (size_t)32 * 1024 * 1024);

    proj_mfma<<<dim3(M_ / 128, D_ / 128, 3), 256, 0, stream>>>(
        q, k, v, Wq, bq, Wk, bk, Wv, bv, qh, qlo, kh, vht);
    attn_mfma<<<dim3(256), 512, 0, stream>>>(qh, qlo, kh, vht, P, attn);
    out_mfma<<<dim3(M_ / 128, D_ / 128), 256, 0, stream>>>(attn, Wo, bo, out);
}

// Round 12
// 403.938 us; speedup vs baseline: 1.1532x; 1.1532x over previous
//
#include <hip/hip_runtime.h>

#define D_  1024
#define H_  16
#define HD_ 64
#define L_  2048
#define B_  2
#define M_  (B_*L_)   // 4096 rows

typedef float f32x4  __attribute__((ext_vector_type(4)));
typedef short bf16x4 __attribute__((ext_vector_type(4)));
typedef short bf16x8 __attribute__((ext_vector_type(8)));

#define SRAW_PITCH 18   // f32 per l-row (72B): conflict-free b64/scalar patterns
#define SRAW_SLAB  (16 * SRAW_PITCH)   // 288 f32 per h (or m) slab
#define VS_PITCH   36   // shorts per d-row (72B)

__device__ __forceinline__ float bf2f(short s) {
    return __uint_as_float(((unsigned int)(unsigned short)s) << 16);
}
__device__ __forceinline__ short f2bf(float f) {   // RNE
    unsigned u = __float_as_uint(f);
    unsigned r = (u + 0x7FFFu + ((u >> 16) & 1u)) >> 16;
    return (short)r;
}
// Raw barrier: orders LDS (lgkmcnt(0) + "memory" clobber), does NOT drain vmcnt.
__device__ __forceinline__ void block_sync() {
    asm volatile("s_waitcnt lgkmcnt(0)" ::: "memory");
    __builtin_amdgcn_sched_barrier(0);
    __builtin_amdgcn_s_barrier();
    __builtin_amdgcn_sched_barrier(0);
}

// ---------------------------------------------------------------------------
// Kernel 1: QKV projections via bf16 MFMA. 128x128 tile, K-step 32, 256 thr.
// z=0: q -> qh(hi)+qlo  [b][h][l][64]        (A=W rows n, B=X cols m: D[n][m])
// z=1: k -> kh          [b][h][l][64]        (same)
// z=2: v -> vht         [b][h][64][L]        (A=X rows m, B=W cols n: D[m][n])
// ---------------------------------------------------------------------------
__global__ __launch_bounds__(256) void proj_mfma(
    const float* __restrict__ q, const float* __restrict__ k, const float* __restrict__ v,
    const float* __restrict__ Wq, const float* __restrict__ bq,
    const float* __restrict__ Wk, const float* __restrict__ bk,
    const float* __restrict__ Wv, const float* __restrict__ bv,
    short* __restrict__ qh, short* __restrict__ qlo,
    short* __restrict__ kh, short* __restrict__ vht)
{
    const int z = blockIdx.z;
    const float* X    = (z == 0) ? q  : (z == 1) ? k  : v;
    const float* W    = (z == 0) ? Wq : (z == 1) ? Wk : Wv;
    const float* bias = (z == 0) ? bq : (z == 1) ? bk : bv;

    __shared__ short Ws[128][40];
    __shared__ short Xs[128][40];

    const int tid  = threadIdx.x;
    const int w    = tid >> 6, lane = tid & 63;
    const int l16  = lane & 15, qq = lane >> 4;
    const int m0   = blockIdx.x * 128;
    const int n0   = blockIdx.y * 128;
    const int ar0  = 64 * (w & 1);
    const int br0  = 64 * (w >> 1);

    f32x4 acc[4][4] = {};

    for (int k0 = 0; k0 < D_; k0 += 32) {
        #pragma unroll
        for (int i = 0; i < 4; ++i) {
            int fidx = i * 256 + tid;
            int r = fidx >> 3, c = fidx & 7;
            float4 wv4 = *(const float4*)(W + (size_t)(n0 + r) * D_ + k0 + c * 4);
            float4 xv4 = *(const float4*)(X + (size_t)(m0 + r) * D_ + k0 + c * 4);
            bf16x4 wb = { f2bf(wv4.x), f2bf(wv4.y), f2bf(wv4.z), f2bf(wv4.w) };
            bf16x4 xb = { f2bf(xv4.x), f2bf(xv4.y), f2bf(xv4.z), f2bf(xv4.w) };
            *(bf16x4*)&Ws[r][c * 4] = wb;
            *(bf16x4*)&Xs[r][c * 4] = xb;
        }
        __syncthreads();
        bf16x8 af[4], bfv[4];
        #pragma unroll
        for (int i = 0; i < 4; ++i) {
            const short* Ab = (z < 2) ? &Ws[ar0 + 16 * i + l16][qq * 8]
                                      : &Xs[ar0 + 16 * i + l16][qq * 8];
            const short* Bb = (z < 2) ? &Xs[br0 + 16 * i + l16][qq * 8]
                                      : &Ws[br0 + 16 * i + l16][qq * 8];
            af[i]  = *(const bf16x8*)Ab;
            bfv[i] = *(const bf16x8*)Bb;
        }
        #pragma unroll
        for (int i = 0; i < 4; ++i)
            #pragma unroll
            for (int j = 0; j < 4; ++j)
                acc[i][j] = __builtin_amdgcn_mfma_f32_16x16x32_bf16(af[i], bfv[j], acc[i][j], 0, 0, 0);
        __syncthreads();
    }

    if (z < 2) {
        #pragma unroll
        for (int i = 0; i < 4; ++i) {
            int nb = n0 + ar0 + 16 * i + qq * 4;
            float4 b4 = *(const float4*)(bias + nb);
            int h = nb >> 6, hd = nb & 63;
            #pragma unroll
            for (int j = 0; j < 4; ++j) {
                int m = m0 + br0 + 16 * j + l16;
                int bb = m >> 11, l = m & (L_ - 1);
                size_t o = ((((size_t)bb * H_ + h) * L_) + l) * HD_ + hd;
                f32x4 c = acc[i][j];
                float v0 = c[0] + b4.x, v1 = c[1] + b4.y, v2 = c[2] + b4.z, v3 = c[3] + b4.w;
                bf16x4 hi = { f2bf(v0), f2bf(v1), f2bf(v2), f2bf(v3) };
                if (z == 0) {
                    *(bf16x4*)&qh[o] = hi;
                    bf16x4 lo = { f2bf(v0 - bf2f(hi[0])), f2bf(v1 - bf2f(hi[1])),
                                  f2bf(v2 - bf2f(hi[2])), f2bf(v3 - bf2f(hi[3])) };
                    *(bf16x4*)&qlo[o] = lo;
                } else {
                    *(bf16x4*)&kh[o] = hi;
                }
            }
        }
    } else {
        // D[m][n]: rows m = m0+ar0+16i+4qq+r ; cols n = n0+br0+16j+l16
        #pragma unroll
        for (int i = 0; i < 4; ++i) {
            int mb = m0 + ar0 + 16 * i + qq * 4;
            int bb = mb >> 11, lb = mb & (L_ - 1);
            #pragma unroll
            for (int j = 0; j < 4; ++j) {
                int n = n0 + br0 + 16 * j + l16;
                int h = n >> 6, hd = n & 63;
                float bn = bias[n];
                size_t o = (((size_t)bb * H_ + h) * HD_ + hd) * (size_t)L_ + lb;
                f32x4 c = acc[i][j];
                bf16x4 ov = { f2bf(c[0] + bn), f2bf(c[1] + bn), f2bf(c[2] + bn), f2bf(c[3] + bn) };
                *(bf16x4*)&vht[o] = ov;
            }
        }
    }
}

// ---------------------------------------------------------------------------
// Kernel 2: fused talking-heads attention. 512 thr (8 waves), l-tile 16,
// KVBLK=32 (two 16-m subtiles a,b per body). Wave w: heads/g {2w,2w+1}.
// R12 = R9's verified pieces (Vslab V path, MFMA mix, deferred-max) with:
//  - single-buffered Sraw (WAR separated by the 2 existing barriers)
//  - two subtiles per body: mix/softmax chains interleave (ILP), barrier
//    rate and rescale rate halved, one K register set (reload after qkt).
// Hazards: (1) Vslab stage-B after PV-A reads: same-wave DS ordering.
// (2) SrawX: mix-reads(t) < B_mid < qkt-writes(t+1);  qkt-writes < B_end <
//     next mix-reads. (3) SmixX: writes(t) < B_mid < reads(t); reads(t) <
//     B_end < writes(t+1).
// ---------------------------------------------------------------------------
__global__ __launch_bounds__(512, 2) void attn_mfma(
    const short* __restrict__ qh, const short* __restrict__ qlo,
    const short* __restrict__ kh, const short* __restrict__ vht,
    const float* __restrict__ P, short* __restrict__ attn_out)
{
    __shared__ __align__(16) float SrawA[16 * SRAW_SLAB];         // [h][l][18] 18.4 KB
    __shared__ __align__(16) float SrawB[16 * SRAW_SLAB];         // 18.4 KB
    __shared__ __align__(16) float SmixA[16 * SRAW_SLAB];         // [m][l][18] (g fast)
    __shared__ __align__(16) float SmixB[16 * SRAW_SLAB];
    __shared__ __align__(16) short Vslab[8][2 * 64 * VS_PITCH];   // 73.7 KB
    __shared__ float PmS[256];

    const int tid  = threadIdx.x;
    const int n    = blockIdx.x;
    const int b    = (n >> 2) & 1;                        // XCD swizzle
    const int l0   = ((n >> 3) * 4 + (n & 3)) * 16;
    const int w    = tid >> 6, lane = tid & 63;
    const int l16  = lane & 15, qq = lane >> 4;
    const size_t hb = (size_t)b * H_;

    // ---- Q frags (persistent)
    bf16x8 qf[2][2][2];
    #pragma unroll
    for (int hh = 0; hh < 2; ++hh)
        #pragma unroll
        for (int kc = 0; kc < 2; ++kc) {
            size_t off = ((hb + 2 * w + hh) * L_ + l0 + l16) * HD_ + kc * 32 + qq * 8;
            qf[hh][kc][0] = *(const bf16x8*)(qh  + off);
            qf[hh][kc][1] = *(const bf16x8*)(qlo + off);
        }

    // V^T staging mapping (i: row = i*32 + (lane>>1); gi = row>>6, d = row&63; vc = lane&1)
    int vgi_[4], vd_[4];
    const int vc = lane & 1;
    #pragma unroll
    for (int i = 0; i < 4; ++i) {
        int vrow = i * 32 + (lane >> 1);
        vgi_[i] = vrow >> 6;
        vd_[i]  = vrow & 63;
    }
    int vwoff[4];
    #pragma unroll
    for (int i = 0; i < 4; ++i)
        vwoff[i] = vgi_[i] * (64 * VS_PITCH) + vd_[i] * VS_PITCH + vc * 8;

    // load helpers
    auto kload = [&](int tile, bf16x8 (&kdst)[2][2]) {
        const int mn = (tile & 127) * 16;
        #pragma unroll
        for (int hh = 0; hh < 2; ++hh)
            #pragma unroll
            for (int kc = 0; kc < 2; ++kc)
                kdst[hh][kc] = *(const bf16x8*)(kh + ((hb + 2 * w + hh) * L_ + mn + l16) * HD_ + kc * 32 + qq * 8);
    };
    auto vload = [&](int tile, bf16x8 (&vdst)[4]) {
        const int mn = (tile & 127) * 16;
        #pragma unroll
        for (int i = 0; i < 4; ++i)
            vdst[i] = *(const bf16x8*)(vht + ((hb + 2 * w + vgi_[i]) * HD_ + vd_[i]) * (size_t)L_ + mn + vc * 8);
    };

    // K: one register set per subtile (consumed by qkt, then reloaded)
    bf16x8 kPa[2][2], kPb[2][2], vsta[4], vstb[4];
    kload(0, kPa); kload(1, kPb);
    vload(0, vsta); vload(1, vstb);

    if (tid < 256) PmS[tid] = P[tid] * 0.125f;            // fold 1/sqrt(64)

    f32x4 acc[2][4];
    #pragma unroll
    for (int dt = 0; dt < 4; ++dt) { acc[0][dt] = (f32x4){0.f,0.f,0.f,0.f}; acc[1][dt] = (f32x4){0.f,0.f,0.f,0.f}; }
    float mrun0 = 0.f, mrun1 = 0.f, srun0 = 0.f, srun1 = 0.f;   // deferred-max

    // QK^T: D[m][l], col=l16, rows m=qq*4+j.  Writes 2x b64 per head slab.
    auto qkt = [&](bf16x8 (&kr)[2][2], float* sb) {
        #pragma unroll
        for (int hh = 0; hh < 2; ++hh) {
            f32x4 s = (f32x4){0.f,0.f,0.f,0.f};
            s = __builtin_amdgcn_mfma_f32_16x16x32_bf16(kr[hh][0], qf[hh][0][0], s, 0, 0, 0);
            s = __builtin_amdgcn_mfma_f32_16x16x32_bf16(kr[hh][0], qf[hh][0][1], s, 0, 0, 0);
            s = __builtin_amdgcn_mfma_f32_16x16x32_bf16(kr[hh][1], qf[hh][1][0], s, 0, 0, 0);
            s = __builtin_amdgcn_mfma_f32_16x16x32_bf16(kr[hh][1], qf[hh][1][1], s, 0, 0, 0);
            float* sp = sb + ((2 * w + hh) * 16 + l16) * SRAW_PITCH + qq * 4;
            *(float2*)sp       = make_float2(s[0], s[1]);
            *(float2*)(sp + 2) = make_float2(s[2], s[3]);
        }
    };

    // prologue: S(tiles 0,1) -> SrawA/B; publish (also PmS)
    qkt(kPa, SrawA);
    qkt(kPb, SrawB);
    block_sync();
    kload(2, kPa); kload(3, kPb);     // consumed by body 0's qkt

    // ---- mix A-operand: P^T hi/lo broadcast fragment (row g=l16, k h=qq*4+j)
    bf16x4 PAhi, PAlo;
    {
        float p0 = PmS[(qq * 4 + 0) * 16 + l16];
        float p1 = PmS[(qq * 4 + 1) * 16 + l16];
        float p2 = PmS[(qq * 4 + 2) * 16 + l16];
        float p3 = PmS[(qq * 4 + 3) * 16 + l16];
        PAhi = (bf16x4){ f2bf(p0), f2bf(p1), f2bf(p2), f2bf(p3) };
        PAlo = (bf16x4){ f2bf(p0 - bf2f(PAhi[0])), f2bf(p1 - bf2f(PAhi[1])),
                         f2bf(p2 - bf2f(PAhi[2])), f2bf(p3 - bf2f(PAhi[3])) };
    }

    // mix via MFMA (2 m-instances per wave): B = scalar-gathered S hi/lo
    auto mixmfma = [&](const float* sb, float* sm) {
        #pragma unroll
        for (int mi = 0; mi < 2; ++mi) {
            const int m = 2 * w + mi;
            float sv0 = sb[(qq * 4 + 0) * SRAW_SLAB + l16 * SRAW_PITCH + m];
            float sv1 = sb[(qq * 4 + 1) * SRAW_SLAB + l16 * SRAW_PITCH + m];
            float sv2 = sb[(qq * 4 + 2) * SRAW_SLAB + l16 * SRAW_PITCH + m];
            float sv3 = sb[(qq * 4 + 3) * SRAW_SLAB + l16 * SRAW_PITCH + m];
            bf16x4 bhi = { f2bf(sv0), f2bf(sv1), f2bf(sv2), f2bf(sv3) };
            bf16x4 blo = { f2bf(sv0 - bf2f(bhi[0])), f2bf(sv1 - bf2f(bhi[1])),
                           f2bf(sv2 - bf2f(bhi[2])), f2bf(sv3 - bf2f(bhi[3])) };
            f32x4 c = (f32x4){0.f, 0.f, 0.f, 0.f};
            c = __builtin_amdgcn_mfma_f32_16x16x16bf16_1k(PAhi, bhi, c, 0, 0, 0);
            c = __builtin_amdgcn_mfma_f32_16x16x16bf16_1k(PAhi, blo, c, 0, 0, 0);
            c = __builtin_amdgcn_mfma_f32_16x16x16bf16_1k(PAlo, bhi, c, 0, 0, 0);
            float* sp = sm + m * SRAW_SLAB + l16 * SRAW_PITCH + qq * 4;
            *(float2*)sp       = make_float2(c[0], c[1]);
            *(float2*)(sp + 2) = make_float2(c[2], c[3]);
        }
    };

    // stage one 16-m subtile's V and run PV with pf0/pf1 (same-wave slab)
    auto stage_pv = [&](bf16x8 (&vst)[4], bf16x4 pf0, bf16x4 pf1) {
        #pragma unroll
        for (int i = 0; i < 4; ++i) {
            bf16x4 wlo = { vst[i][0], vst[i][1], vst[i][2], vst[i][3] };
            bf16x4 whi = { vst[i][4], vst[i][5], vst[i][6], vst[i][7] };
            *(bf16x4*)&Vslab[w][vwoff[i]]     = wlo;
            *(bf16x4*)&Vslab[w][vwoff[i] + 4] = whi;
        }
        #pragma unroll
        for (int i = 0; i < 2; ++i) {
            bf16x4 pf = i ? pf1 : pf0;
            #pragma unroll
            for (int dt = 0; dt < 4; ++dt) {
                bf16x4 afr = *(const bf16x4*)&Vslab[w][i * (64 * VS_PITCH) + (dt * 16 + l16) * VS_PITCH + qq * 4];
                acc[i][dt] = __builtin_amdgcn_mfma_f32_16x16x16bf16_1k(afr, pf, acc[i][dt], 0, 0, 0);
            }
        }
    };

    for (int t = 0; t < 64; ++t) {
        // 1. mix both subtiles (independent MFMA chains -> ILP)
        mixmfma(SrawA, SmixA);
        mixmfma(SrawB, SmixB);
        block_sync();   // B_mid: Smix visible; mix-reads of Sraw complete
        // 2. softmax inputs for both subtiles, both g
        float sxA0[4], sxA1[4], sxB0[4], sxB1[4];
        #pragma unroll
        for (int j = 0; j < 4; ++j) {
            const float* mpA = SmixA + (qq * 4 + j) * SRAW_SLAB + l16 * SRAW_PITCH;
            const float* mpB = SmixB + (qq * 4 + j) * SRAW_SLAB + l16 * SRAW_PITCH;
            sxA0[j] = mpA[2 * w]; sxA1[j] = mpA[2 * w + 1];
            sxB0[j] = mpB[2 * w]; sxB1[j] = mpB[2 * w + 1];
        }
        // 3. deferred-max exps (all vs m_old; 16 independent exps)
        float eA00 = __expf(sxA0[0] - mrun0), eA01 = __expf(sxA0[1] - mrun0);
        float eA02 = __expf(sxA0[2] - mrun0), eA03 = __expf(sxA0[3] - mrun0);
        float eA10 = __expf(sxA1[0] - mrun1), eA11 = __expf(sxA1[1] - mrun1);
        float eA12 = __expf(sxA1[2] - mrun1), eA13 = __expf(sxA1[3] - mrun1);
        float eB00 = __expf(sxB0[0] - mrun0), eB01 = __expf(sxB0[1] - mrun0);
        float eB02 = __expf(sxB0[2] - mrun0), eB03 = __expf(sxB0[3] - mrun0);
        float eB10 = __expf(sxB1[0] - mrun1), eB11 = __expf(sxB1[1] - mrun1);
        float eB12 = __expf(sxB1[2] - mrun1), eB13 = __expf(sxB1[3] - mrun1);
        bf16x4 pfA0 = { f2bf(eA00), f2bf(eA01), f2bf(eA02), f2bf(eA03) };
        bf16x4 pfA1 = { f2bf(eA10), f2bf(eA11), f2bf(eA12), f2bf(eA13) };
        bf16x4 pfB0 = { f2bf(eB00), f2bf(eB01), f2bf(eB02), f2bf(eB03) };
        bf16x4 pfB1 = { f2bf(eB10), f2bf(eB11), f2bf(eB12), f2bf(eB13) };
        // max/sum reduces (off PV critical path)
        float t0 = fmaxf(fmaxf(fmaxf(sxA0[0], sxA0[1]), fmaxf(sxA0[2], sxA0[3])),
                         fmaxf(fmaxf(sxB0[0], sxB0[1]), fmaxf(sxB0[2], sxB0[3])));
        float t1 = fmaxf(fmaxf(fmaxf(sxA1[0], sxA1[1]), fmaxf(sxA1[2], sxA1[3])),
                         fmaxf(fmaxf(sxB1[0], sxB1[1]), fmaxf(sxB1[2], sxB1[3])));
        t0 = fmaxf(t0, __shfl_xor(t0, 16)); t0 = fmaxf(t0, __shfl_xor(t0, 32));
        t1 = fmaxf(t1, __shfl_xor(t1, 16)); t1 = fmaxf(t1, __shfl_xor(t1, 32));
        float ps0 = (eA00 + eA01 + eA02 + eA03) + (eB00 + eB01 + eB02 + eB03);
        float ps1 = (eA10 + eA11 + eA12 + eA13) + (eB10 + eB11 + eB12 + eB13);
        ps0 += __shfl_xor(ps0, 16); ps0 += __shfl_xor(ps0, 32);
        ps1 += __shfl_xor(ps1, 16); ps1 += __shfl_xor(ps1, 32);
        // 4. PV subtile a, refill vsta; then subtile b (same-wave slab reuse)
        stage_pv(vsta, pfA0, pfA1);
        vload(2 * t + 2, vsta);
        stage_pv(vstb, pfB0, pfB1);
        vload(2 * t + 3, vstb);
        // 5. QK^T for next body's tiles (kP consumed, then reloaded)
        qkt(kPa, SrawA);
        qkt(kPb, SrawB);
        kload(2 * t + 4, kPa);
        kload(2 * t + 5, kPb);
        // 6. one rescale per 32 m
        float mnew0 = fmaxf(mrun0, t0), mnew1 = fmaxf(mrun1, t1);
        float corr0 = __expf(mrun0 - mnew0), corr1 = __expf(mrun1 - mnew1);
        srun0 = (srun0 + ps0) * corr0; srun1 = (srun1 + ps1) * corr1;
        acc[0][0] *= corr0; acc[0][1] *= corr0; acc[0][2] *= corr0; acc[0][3] *= corr0;
        acc[1][0] *= corr1; acc[1][1] *= corr1; acc[1][2] *= corr1; acc[1][3] *= corr1;
        mrun0 = mnew0; mrun1 = mnew1;
        block_sync();   // B_end
    }

    // epilogue: D[d][l] -> out[b][l][g*64 + d]
    float inv0 = 1.f / srun0, inv1 = 1.f / srun1;
    #pragma unroll
    for (int i = 0; i < 2; ++i) {
        float inv = i ? inv1 : inv0;
        #pragma unroll
        for (int dt = 0; dt < 4; ++dt) {
            f32x4 a = acc[i][dt];
            bf16x4 ov = { f2bf(a[0] * inv), f2bf(a[1] * inv), f2bf(a[2] * inv), f2bf(a[3] * inv) };
            *(bf16x4*)(attn_out + ((size_t)(b * L_ + l0 + l16)) * D_ + (2 * w + i) * 64 + dt * 16 + qq * 4) = ov;
        }
    }
}

// ---------------------------------------------------------------------------
// Kernel 3: output projection (attn bf16 @ Wo^T + bo) -> f32, MFMA.
// ---------------------------------------------------------------------------
__global__ __launch_bounds__(256) void out_mfma(
    const short* __restrict__ attn, const float* __restrict__ Wo,
    const float* __restrict__ bo, float* __restrict__ out)
{
    __shared__ short Ws[128][40];
    __shared__ short Xs[128][40];

    const int tid = threadIdx.x;
    const int w = tid >> 6, lane = tid & 63;
    const int l16 = lane & 15, qq = lane >> 4;
    const int m0 = blockIdx.x * 128;
    const int n0 = blockIdx.y * 128;
    const int ar0 = 64 * (w & 1);
    const int br0 = 64 * (w >> 1);

    f32x4 acc[4][4] = {};

    for (int k0 = 0; k0 < D_; k0 += 32) {
        #pragma unroll
        for (int i = 0; i < 4; ++i) {
            int fidx = i * 256 + tid;
            int r = fidx >> 3, c = fidx & 7;
            float4 wv4 = *(const float4*)(Wo + (size_t)(n0 + r) * D_ + k0 + c * 4);
            bf16x4 wb = { f2bf(wv4.x), f2bf(wv4.y), f2bf(wv4.z), f2bf(wv4.w) };
            *(bf16x4*)&Ws[r][c * 4] = wb;
        }
        #pragma unroll
        for (int i = 0; i < 2; ++i) {
            int cidx = i * 256 + tid;
            int r = cidx >> 2, c = cidx & 3;
            bf16x8 xv = *(const bf16x8*)(attn + (size_t)(m0 + r) * D_ + k0 + c * 8);
            *(bf16x8*)&Xs[r][c * 8] = xv;
        }
        __syncthreads();
        bf16x8 af[4], bfv[4];
        #pragma unroll
        for (int i = 0; i < 4; ++i) {
            af[i]  = *(const bf16x8*)&Ws[ar0 + 16 * i + l16][qq * 8];
            bfv[i] = *(const bf16x8*)&Xs[br0 + 16 * i + l16][qq * 8];
        }
        #pragma unroll
        for (int i = 0; i < 4; ++i)
            #pragma unroll
            for (int j = 0; j < 4; ++j)
                acc[i][j] = __builtin_amdgcn_mfma_f32_16x16x32_bf16(af[i], bfv[j], acc[i][j], 0, 0, 0);
        __syncthreads();
    }

    #pragma unroll
    for (int i = 0; i < 4; ++i) {
        int nb = n0 + ar0 + 16 * i + qq * 4;
        float4 b4 = *(const float4*)(bo + nb);
        #pragma unroll
        for (int j = 0; j < 4; ++j) {
            int m = m0 + br0 + 16 * j + l16;
            f32x4 c = acc[i][j];
            float4 ov = make_float4(c[0] + b4.x, c[1] + b4.y, c[2] + b4.z, c[3] + b4.w);
            *(float4*)&out[(size_t)m * D_ + nb] = ov;
        }
    }
}

// ---------------------------------------------------------------------------
extern "C" void kernel_launch(void* const* d_in, const int* in_sizes, int n_in,
                              void* d_out, int out_size, void* d_ws, size_t ws_size,
                              hipStream_t stream) {
    const float* q  = (const float*)d_in[0];
    const float* k  = (const float*)d_in[1];
    const float* v  = (const float*)d_in[2];
    const float* Wq = (const float*)d_in[3];
    const float* bq = (const float*)d_in[4];
    const float* Wk = (const float*)d_in[5];
    const float* bk = (const float*)d_in[6];
    const float* Wv = (const float*)d_in[7];
    const float* bv = (const float*)d_in[8];
    const float* Wo = (const float*)d_in[9];
    const float* bo = (const float*)d_in[10];
    const float* P  = (const float*)d_in[11];
    float* out = (float*)d_out;

    // ws: qh 8MB | qlo 8MB | kh 8MB | vht 8MB | attn 8MB (all bf16/short)
    char* ws = (char*)d_ws;
    short* qh   = (short*)(ws);
    short* qlo  = (short*)(ws + (size_t)8 * 1024 * 1024);
    short* kh   = (short*)(ws + (size_t)16 * 1024 * 1024);
    short* vht  = (short*)(ws + (size_t)24 * 1024 * 1024);
    short* attn = (short*)(ws + (size_t)32 * 1024 * 1024);

    proj_mfma<<<dim3(M_ / 128, D_ / 128, 3), 256, 0, stream>>>(
        q, k, v, Wq, bq, Wk, bk, Wv, bv, qh, qlo, kh, vht);
    attn_mfma<<<dim3(256), 512, 0, stream>>>(qh, qlo, kh, vht, P, attn);
    out_mfma<<<dim3(M_ / 128, D_ / 128), 256, 0, stream>>>(attn, Wo, bo, out);
}